// Round 6
// baseline (438.725 us; speedup 1.0000x reference)
//
#include <hip/hip_runtime.h>
#include <hip/hip_bf16.h>
#include <cstdint>

typedef unsigned short u16;
typedef __attribute__((ext_vector_type(8))) short bh8;   // 8 bf16 (4 VGPR)
typedef __attribute__((ext_vector_type(4))) short sh4;   // 4 bf16
typedef __attribute__((ext_vector_type(4))) float fx4;

#define NTOK 2048
#define HDIM 1024
#define NE 8
#define FDIM 2048

__device__ __forceinline__ u16 f2bf(float f) {
    __hip_bfloat16 h = __float2bfloat16(f);
    return __builtin_bit_cast(u16, h);
}

// async global->LDS, 16B per lane. LDS dest is wave-uniform base (+lane*16 implicit).
__device__ __forceinline__ void gll16(const void* g, void* l) {
    __builtin_amdgcn_global_load_lds(
        (const __attribute__((address_space(1))) void*)g,
        (__attribute__((address_space(3))) void*)l, 16, 0, 0);
}

// ---------------------------------------------------------- f32 -> bf16 convert
__global__ __launch_bounds__(256)
void convert_k(const float* __restrict__ S, u16* __restrict__ D, int n8) {
    int i = blockIdx.x * 256 + threadIdx.x;
    const int stride = gridDim.x * 256;
    for (; i < n8; i += stride) {
        const fx4 a = *(const fx4*)&S[(size_t)i * 8];
        const fx4 b = *(const fx4*)&S[(size_t)i * 8 + 4];
        bh8 o;
        #pragma unroll
        for (int j = 0; j < 4; ++j) {
            o[j]     = (short)f2bf(a[j]);
            o[j + 4] = (short)f2bf(b[j]);
        }
        *(bh8*)&D[(size_t)i * 8] = o;
    }
}

// ---------------------------------------------------------------- rope table
__global__ __launch_bounds__(256)
void rope_table_k(float* __restrict__ cosT, float* __restrict__ sinT) {
    int idx = blockIdx.x * 256 + threadIdx.x;      // 2048*32
    int t = idx >> 5, i = idx & 31;
    float freq = powf(10000.0f, -(float)i * (1.0f / 32.0f));
    float ang = (float)t * freq;
    float s, c;
    sincosf(ang, &s, &c);
    cosT[idx] = c;
    sinT[idx] = s;
}

// ---------------------------------------------------------------- rmsnorm 1
__global__ __launch_bounds__(256)
void rmsnorm_k(const float* __restrict__ X, const float* __restrict__ W, u16* __restrict__ O) {
    const int t = blockIdx.x;
    const int tid = threadIdx.x;
    const fx4 v = *(const fx4*)&X[(size_t)t * HDIM + tid * 4];
    float ss = v[0]*v[0] + v[1]*v[1] + v[2]*v[2] + v[3]*v[3];
    #pragma unroll
    for (int o = 1; o < 64; o <<= 1) ss += __shfl_xor(ss, o);
    __shared__ float red[4];
    if ((tid & 63) == 0) red[tid >> 6] = ss;
    __syncthreads();
    const float inv = rsqrtf((red[0] + red[1] + red[2] + red[3]) * (1.0f / HDIM) + 1e-5f);
    const fx4 w = *(const fx4*)&W[tid * 4];
    sh4 o4;
    #pragma unroll
    for (int i = 0; i < 4; ++i) o4[i] = (short)f2bf(v[i] * inv * w[i]);
    *(sh4*)&O[(size_t)t * HDIM + tid * 4] = o4;
}

// -------------------------------------------- rmsnorm 2 + router logits (f32)
__global__ __launch_bounds__(256)
void rmsnorm2_router_k(const float* __restrict__ X, const float* __restrict__ W,
                       const float* __restrict__ GW, u16* __restrict__ O,
                       float* __restrict__ LOGI) {
    const int t = blockIdx.x;
    const int tid = threadIdx.x;
    const fx4 v = *(const fx4*)&X[(size_t)t * HDIM + tid * 4];
    float ss = v[0]*v[0] + v[1]*v[1] + v[2]*v[2] + v[3]*v[3];
    #pragma unroll
    for (int o = 1; o < 64; o <<= 1) ss += __shfl_xor(ss, o);
    __shared__ float red[4];
    if ((tid & 63) == 0) red[tid >> 6] = ss;
    __syncthreads();
    const float inv = rsqrtf((red[0] + red[1] + red[2] + red[3]) * (1.0f / HDIM) + 1e-5f);
    const fx4 w = *(const fx4*)&W[tid * 4];
    fx4 xn;
    #pragma unroll
    for (int i = 0; i < 4; ++i) xn[i] = v[i] * inv * w[i];
    sh4 o4;
    #pragma unroll
    for (int i = 0; i < 4; ++i) o4[i] = (short)f2bf(xn[i]);
    *(sh4*)&O[(size_t)t * HDIM + tid * 4] = o4;

    float part[NE];
    #pragma unroll
    for (int e = 0; e < NE; ++e) {
        const fx4 g = *(const fx4*)&GW[(size_t)e * HDIM + tid * 4];
        part[e] = g[0]*xn[0] + g[1]*xn[1] + g[2]*xn[2] + g[3]*xn[3];
    }
    #pragma unroll
    for (int e = 0; e < NE; ++e)
        #pragma unroll
        for (int o = 1; o < 64; o <<= 1) part[e] += __shfl_xor(part[e], o);
    __shared__ float red8[4][NE];
    if ((tid & 63) == 0) {
        #pragma unroll
        for (int e = 0; e < NE; ++e) red8[tid >> 6][e] = part[e];
    }
    __syncthreads();
    if (tid < NE)
        LOGI[(size_t)t * NE + tid] = red8[0][tid] + red8[1][tid] + red8[2][tid] + red8[3][tid];
}

// ---------------------------------------------------------------- router top2
__global__ __launch_bounds__(256)
void router_topk_k(const float* __restrict__ LOGI, int* __restrict__ counts,
                   int* __restrict__ tokslot, float* __restrict__ wtb) {
    const int t = blockIdx.x * 256 + threadIdx.x;
    float l[NE];
    #pragma unroll
    for (int e = 0; e < NE; ++e) l[e] = LOGI[(size_t)t * NE + e];
    int i0 = 0;
    #pragma unroll
    for (int e = 1; e < NE; ++e) if (l[e] > l[i0]) i0 = e;
    int i1 = (i0 == 0) ? 1 : 0;
    #pragma unroll
    for (int e = 0; e < NE; ++e) if (e != i0 && l[e] > l[i1]) i1 = e;
    float e1 = __expf(l[i1] - l[i0]);
    float w0 = 1.0f / (1.0f + e1);
    float w1 = 1.0f - w0;
    int p0 = atomicAdd(&counts[i0], 1);
    tokslot[i0 * NTOK + p0] = t * 2;
    wtb[i0 * NTOK + p0] = w0;
    int p1 = atomicAdd(&counts[i1], 1);
    tokslot[i1 * NTOK + p1] = t * 2 + 1;
    wtb[i1 * NTOK + p1] = w1;
}

// ------------------------------------------------------------- generic GEMM
// C[M,N] = A_bf16[M,K] @ B_bf16[N,K]^T ; 64x64 tile, BK=32, 4 waves (wave = 16 rows).
// A fragments loaded per-lane from global (no LDS); B via gll dbuf with XOR-swizzle.
// Swizzle: LDS 16B-seg = g ^ ((row>>1)&3); staging source seg = (t&3)^((t>>3)&3).
// EPI: 1 = f32 + residual ; 2 = bf16 ; 3 = bf16 + RoPE
template<int EPI>
__global__ __launch_bounds__(256)
void gemm_bt(const u16* __restrict__ A, const u16* __restrict__ B,
             u16* __restrict__ Cb, float* __restrict__ Cf,
             const int N, const int K,
             const float* __restrict__ aux0, const float* __restrict__ aux1) {
    __shared__ u16 Bs[2][64 * 32];

    const int tid = threadIdx.x;
    const int lane = tid & 63;
    const int wid = tid >> 6;
    const int lrow = lane & 15, lgrp = lane >> 4;
    const int wm = wid * 16;
    const int soff = (lgrp ^ ((lrow >> 1) & 3)) * 8;

    const int m0 = blockIdx.y * 64;
    const int n0 = blockIdx.x * 64;

    const int gseg = ((tid & 3) ^ ((tid >> 3) & 3)) * 8;
    const u16* bpg = B + (size_t)(n0 + (tid >> 2)) * K + gseg;
    const u16* apg = A + (size_t)(m0 + wm + lrow) * K + lgrp * 8;

    fx4 acc[4];
    #pragma unroll
    for (int i = 0; i < 4; ++i) acc[i] = fx4{0.f, 0.f, 0.f, 0.f};

    gll16(bpg, &Bs[0][wid * 512]);
    bh8 a0 = *(const bh8*)(apg);
    bh8 a1;

    for (int k0 = 0; k0 < K; k0 += 64) {
        // half 0: compute k0 (Bs[0]); stage k0+32 -> Bs[1]
        __syncthreads();
        gll16(bpg + k0 + 32, &Bs[1][wid * 512]);
        a1 = *(const bh8*)(apg + k0 + 32);
        #pragma unroll
        for (int ni = 0; ni < 4; ++ni) {
            const bh8 bf = *(const bh8*)&Bs[0][(ni * 16 + lrow) * 32 + soff];
            acc[ni] = __builtin_amdgcn_mfma_f32_16x16x32_bf16(a0, bf, acc[ni], 0, 0, 0);
        }
        // half 1: compute k0+32 (Bs[1]); stage k0+64 -> Bs[0]
        __syncthreads();
        if (k0 + 64 < K) {
            gll16(bpg + k0 + 64, &Bs[0][wid * 512]);
            a0 = *(const bh8*)(apg + k0 + 64);
        }
        #pragma unroll
        for (int ni = 0; ni < 4; ++ni) {
            const bh8 bf = *(const bh8*)&Bs[1][(ni * 16 + lrow) * 32 + soff];
            acc[ni] = __builtin_amdgcn_mfma_f32_16x16x32_bf16(a1, bf, acc[ni], 0, 0, 0);
        }
    }

    #pragma unroll
    for (int j = 0; j < 4; ++j) {
        const int r = m0 + wm + lgrp * 4 + j;
        if (EPI == 3) {
            #pragma unroll
            for (int ni = 0; ni < 2; ++ni) {
                const int d = ni * 16 + lrow;            // d < 32
                const float cv = aux0[r * 32 + d];
                const float sv = aux1[r * 32 + d];
                const float v0 = acc[ni][j];
                const float v1 = acc[ni + 2][j];
                Cb[(size_t)r * N + n0 + d]      = f2bf(v0 * cv - v1 * sv);
                Cb[(size_t)r * N + n0 + d + 32] = f2bf(v1 * cv + v0 * sv);
            }
        } else {
            #pragma unroll
            for (int ni = 0; ni < 4; ++ni) {
                const int c = n0 + ni * 16 + lrow;
                const float v = acc[ni][j];
                if (EPI == 1) Cf[(size_t)r * N + c] = v + aux0[(size_t)r * N + c];
                if (EPI == 2) Cb[(size_t)r * N + c] = f2bf(v);
            }
        }
    }
}

// --------------------------------------------------------- flash attention
__global__ __launch_bounds__(256)
void attn_kernel(const u16* __restrict__ Q, const u16* __restrict__ Kg,
                 const u16* __restrict__ Vg, u16* __restrict__ O) {
    const int qt = blockIdx.x;
    const int h = blockIdx.y;
    const int kvh = h >> 2;

    const int tid = threadIdx.x;
    const int lane = tid & 63;
    const int wid = tid >> 6;
    const int lrow = lane & 15, lgrp = lane >> 4;

    __shared__ u16 Ks[64 * 72];
    __shared__ u16 Vs[64 * 72];
    __shared__ u16 Ps[4][32 * 72];

    const int qbase = qt * 128 + wid * 32;

    bh8 qf[2][2];
    #pragma unroll
    for (int mi = 0; mi < 2; ++mi)
        #pragma unroll
        for (int kf = 0; kf < 2; ++kf)
            qf[mi][kf] = *(const bh8*)&Q[(size_t)(qbase + mi * 16 + lrow) * 1024 + h * 64 + kf * 32 + lgrp * 8];

    fx4 acc[2][4];
    #pragma unroll
    for (int mi = 0; mi < 2; ++mi)
        #pragma unroll
        for (int ni = 0; ni < 4; ++ni) acc[mi][ni] = fx4{0.f, 0.f, 0.f, 0.f};
    float mrun[2][4], lrun[2][4];
    #pragma unroll
    for (int mi = 0; mi < 2; ++mi)
        #pragma unroll
        for (int j = 0; j < 4; ++j) { mrun[mi][j] = -1e30f; lrun[mi][j] = 0.f; }

    const int srow = tid >> 2;
    const int sseg = (tid & 3) * 16;

    const int ntiles = qt * 2 + 2;

    size_t goff = (size_t)(srow) * 256 + kvh * 64 + sseg;
    bh8 kva = *(const bh8*)&Kg[goff];
    bh8 kvb = *(const bh8*)&Kg[goff + 8];
    bh8 vva = *(const bh8*)&Vg[goff];
    bh8 vvb = *(const bh8*)&Vg[goff + 8];

    for (int it = 0; it < ntiles; ++it) {
        const int kv0 = it * 64;
        __syncthreads();
        *(bh8*)&Ks[srow * 72 + sseg] = kva;
        *(bh8*)&Ks[srow * 72 + sseg + 8] = kvb;
        #pragma unroll
        for (int jj = 0; jj < 8; ++jj) {
            Vs[(sseg + jj) * 72 + srow]     = (u16)vva[jj];
            Vs[(sseg + 8 + jj) * 72 + srow] = (u16)vvb[jj];
        }
        __syncthreads();

        const int itn = (it + 1 < ntiles) ? it + 1 : it;
        const size_t goff2 = (size_t)(itn * 64 + srow) * 256 + kvh * 64 + sseg;
        kva = *(const bh8*)&Kg[goff2];
        kvb = *(const bh8*)&Kg[goff2 + 8];
        vva = *(const bh8*)&Vg[goff2];
        vvb = *(const bh8*)&Vg[goff2 + 8];

        fx4 s[2][4];
        #pragma unroll
        for (int mi = 0; mi < 2; ++mi)
            #pragma unroll
            for (int nf = 0; nf < 4; ++nf) s[mi][nf] = fx4{0.f, 0.f, 0.f, 0.f};
        #pragma unroll
        for (int kf = 0; kf < 2; ++kf) {
            bh8 kfr[4];
            #pragma unroll
            for (int nf = 0; nf < 4; ++nf)
                kfr[nf] = *(const bh8*)&Ks[(nf * 16 + lrow) * 72 + kf * 32 + lgrp * 8];
            #pragma unroll
            for (int mi = 0; mi < 2; ++mi)
                #pragma unroll
                for (int nf = 0; nf < 4; ++nf)
                    s[mi][nf] = __builtin_amdgcn_mfma_f32_16x16x32_bf16(qf[mi][kf], kfr[nf], s[mi][nf], 0, 0, 0);
        }

        #pragma unroll
        for (int mi = 0; mi < 2; ++mi)
            #pragma unroll
            for (int nf = 0; nf < 4; ++nf)
                #pragma unroll
                for (int j = 0; j < 4; ++j) {
                    const int qr = qbase + mi * 16 + lgrp * 4 + j;
                    const int kp = kv0 + nf * 16 + lrow;
                    const float v = s[mi][nf][j] * 0.125f;
                    s[mi][nf][j] = (kp > qr) ? -1e30f : v;
                }

        #pragma unroll
        for (int mi = 0; mi < 2; ++mi)
            #pragma unroll
            for (int j = 0; j < 4; ++j) {
                float mx = fmaxf(fmaxf(s[mi][0][j], s[mi][1][j]), fmaxf(s[mi][2][j], s[mi][3][j]));
                #pragma unroll
                for (int o = 1; o < 16; o <<= 1) mx = fmaxf(mx, __shfl_xor(mx, o));
                const float mnew = fmaxf(mrun[mi][j], mx);
                const float alpha = __expf(mrun[mi][j] - mnew);
                mrun[mi][j] = mnew;
                float rsum = 0.f;
                #pragma unroll
                for (int nf = 0; nf < 4; ++nf) {
                    const float p = __expf(s[mi][nf][j] - mnew);
                    s[mi][nf][j] = p;
                    rsum += p;
                }
                #pragma unroll
                for (int o = 1; o < 16; o <<= 1) rsum += __shfl_xor(rsum, o);
                lrun[mi][j] = lrun[mi][j] * alpha + rsum;
                #pragma unroll
                for (int ni = 0; ni < 4; ++ni) acc[mi][ni][j] *= alpha;
            }

        u16* pw = Ps[wid];
        #pragma unroll
        for (int mi = 0; mi < 2; ++mi)
            #pragma unroll
            for (int nf = 0; nf < 4; ++nf)
                #pragma unroll
                for (int j = 0; j < 4; ++j)
                    pw[(mi * 16 + lgrp * 4 + j) * 72 + nf * 16 + lrow] = f2bf(s[mi][nf][j]);

        #pragma unroll
        for (int kf = 0; kf < 2; ++kf) {
            bh8 pa[2];
            #pragma unroll
            for (int mi = 0; mi < 2; ++mi)
                pa[mi] = *(const bh8*)&pw[(mi * 16 + lrow) * 72 + kf * 32 + lgrp * 8];
            #pragma unroll
            for (int ni = 0; ni < 4; ++ni) {
                bh8 vb = *(const bh8*)&Vs[(ni * 16 + lrow) * 72 + kf * 32 + lgrp * 8];
                #pragma unroll
                for (int mi = 0; mi < 2; ++mi)
                    acc[mi][ni] = __builtin_amdgcn_mfma_f32_16x16x32_bf16(pa[mi], vb, acc[mi][ni], 0, 0, 0);
            }
        }
    }

    #pragma unroll
    for (int mi = 0; mi < 2; ++mi)
        #pragma unroll
        for (int j = 0; j < 4; ++j) {
            const float inv = 1.0f / lrun[mi][j];
            const int r = qbase + mi * 16 + lgrp * 4 + j;
            #pragma unroll
            for (int ni = 0; ni < 4; ++ni)
                O[(size_t)r * 1024 + h * 64 + ni * 16 + lrow] = f2bf(acc[mi][ni][j] * inv);
        }
}

// ------------------------------------------------- MoE up (w1,w3 + SiLU*mul)
// 64x128 tile, 4 waves (2x2; wave = 32m x 64n). A per-lane from global (token gather),
// B1/B3 gll dbuf swizzled (32KB LDS).
__global__ __launch_bounds__(256)
void moe_up_k(const u16* __restrict__ X, const u16* __restrict__ W1b,
              const u16* __restrict__ W3b, const int* __restrict__ counts,
              const int* __restrict__ tokslot, u16* __restrict__ G) {
    const int e = blockIdx.z;
    const int cnt = counts[e];
    const int m0 = blockIdx.y * 64;
    if (m0 >= cnt) return;
    const int n0 = blockIdx.x * 128;

    __shared__ u16 B1s[2][128 * 32];
    __shared__ u16 B3s[2][128 * 32];

    const int tid = threadIdx.x;
    const int lane = tid & 63, wid = tid >> 6;
    const int wm = (wid >> 1) * 32, wn = (wid & 1) * 64;
    const int lrow = lane & 15, lgrp = lane >> 4;
    const int soff = (lgrp ^ ((lrow >> 1) & 3)) * 8;

    // A rows (token-gathered): two per thread
    const int r0i = m0 + wm + lrow;
    const int r1i = r0i + 16;
    const int tk0 = (r0i < cnt) ? (tokslot[e * NTOK + r0i] >> 1) : 0;
    const int tk1 = (r1i < cnt) ? (tokslot[e * NTOK + r1i] >> 1) : 0;
    const u16* ap0 = X + (size_t)tk0 * HDIM + lgrp * 8;
    const u16* ap1 = X + (size_t)tk1 * HDIM + lgrp * 8;

    const int gseg = ((tid & 3) ^ ((tid >> 3) & 3)) * 8;
    const size_t eoff = (size_t)e * FDIM * HDIM;
    const u16* b1pg = W1b + eoff + (size_t)(n0 + (tid >> 2)) * HDIM + gseg;
    const u16* b3pg = W3b + eoff + (size_t)(n0 + (tid >> 2)) * HDIM + gseg;
    const size_t sw2 = (size_t)64 * HDIM;   // sweep-1 row offset

    fx4 acc1[2][4], acc3[2][4];
    #pragma unroll
    for (int i = 0; i < 2; ++i)
        #pragma unroll
        for (int j = 0; j < 4; ++j) {
            acc1[i][j] = fx4{0.f, 0.f, 0.f, 0.f};
            acc3[i][j] = fx4{0.f, 0.f, 0.f, 0.f};
        }

    gll16(b1pg, &B1s[0][wid * 512]);
    gll16(b1pg + sw2, &B1s[0][2048 + wid * 512]);
    gll16(b3pg, &B3s[0][wid * 512]);
    gll16(b3pg + sw2, &B3s[0][2048 + wid * 512]);
    bh8 a00 = *(const bh8*)(ap0);
    bh8 a01 = *(const bh8*)(ap1);
    bh8 a10, a11;

    for (int k0 = 0; k0 < HDIM; k0 += 64) {
        // half 0: compute k0 (buf0); stage k0+32 -> buf1
        __syncthreads();
        {
            const int kn = k0 + 32;
            gll16(b1pg + kn, &B1s[1][wid * 512]);
            gll16(b1pg + sw2 + kn, &B1s[1][2048 + wid * 512]);
            gll16(b3pg + kn, &B3s[1][wid * 512]);
            gll16(b3pg + sw2 + kn, &B3s[1][2048 + wid * 512]);
            a10 = *(const bh8*)(ap0 + kn);
            a11 = *(const bh8*)(ap1 + kn);
        }
        #pragma unroll
        for (int ni = 0; ni < 4; ++ni) {
            const int ro = (wn + ni * 16 + lrow) * 32 + soff;
            const bh8 b1f = *(const bh8*)&B1s[0][ro];
            const bh8 b3f = *(const bh8*)&B3s[0][ro];
            acc1[0][ni] = __builtin_amdgcn_mfma_f32_16x16x32_bf16(a00, b1f, acc1[0][ni], 0, 0, 0);
            acc3[0][ni] = __builtin_amdgcn_mfma_f32_16x16x32_bf16(a00, b3f, acc3[0][ni], 0, 0, 0);
            acc1[1][ni] = __builtin_amdgcn_mfma_f32_16x16x32_bf16(a01, b1f, acc1[1][ni], 0, 0, 0);
            acc3[1][ni] = __builtin_amdgcn_mfma_f32_16x16x32_bf16(a01, b3f, acc3[1][ni], 0, 0, 0);
        }
        // half 1: compute k0+32 (buf1); stage k0+64 -> buf0
        __syncthreads();
        if (k0 + 64 < HDIM) {
            const int kn = k0 + 64;
            gll16(b1pg + kn, &B1s[0][wid * 512]);
            gll16(b1pg + sw2 + kn, &B1s[0][2048 + wid * 512]);
            gll16(b3pg + kn, &B3s[0][wid * 512]);
            gll16(b3pg + sw2 + kn, &B3s[0][2048 + wid * 512]);
            a00 = *(const bh8*)(ap0 + kn);
            a01 = *(const bh8*)(ap1 + kn);
        }
        #pragma unroll
        for (int ni = 0; ni < 4; ++ni) {
            const int ro = (wn + ni * 16 + lrow) * 32 + soff;
            const bh8 b1f = *(const bh8*)&B1s[1][ro];
            const bh8 b3f = *(const bh8*)&B3s[1][ro];
            acc1[0][ni] = __builtin_amdgcn_mfma_f32_16x16x32_bf16(a10, b1f, acc1[0][ni], 0, 0, 0);
            acc3[0][ni] = __builtin_amdgcn_mfma_f32_16x16x32_bf16(a10, b3f, acc3[0][ni], 0, 0, 0);
            acc1[1][ni] = __builtin_amdgcn_mfma_f32_16x16x32_bf16(a11, b1f, acc1[1][ni], 0, 0, 0);
            acc3[1][ni] = __builtin_amdgcn_mfma_f32_16x16x32_bf16(a11, b3f, acc3[1][ni], 0, 0, 0);
        }
    }

    #pragma unroll
    for (int mi = 0; mi < 2; ++mi)
        #pragma unroll
        for (int j = 0; j < 4; ++j) {
            const int r = m0 + wm + mi * 16 + lgrp * 4 + j;
            if (r < cnt) {
                #pragma unroll
                for (int ni = 0; ni < 4; ++ni) {
                    const int c = n0 + wn + ni * 16 + lrow;
                    const float h1 = acc1[mi][ni][j];
                    const float h3 = acc3[mi][ni][j];
                    const float gv = h1 / (1.0f + __expf(-h1)) * h3;
                    G[((size_t)e * NTOK + r) * FDIM + c] = f2bf(gv);
                }
            }
        }
}

// -------------------------------------------------- MoE down (scaled scatter)
// 64x64 tile, 4 waves (wave = 16 rows), K=2048. A per-lane global, B gll dbuf swizzled.
__global__ __launch_bounds__(256)
void moe_down_k(const u16* __restrict__ G, const u16* __restrict__ W2b,
                const int* __restrict__ counts, const int* __restrict__ tokslot,
                const float* __restrict__ wtb, float* __restrict__ MO) {
    const int e = blockIdx.z;
    const int cnt = counts[e];
    const int m0 = blockIdx.y * 64;
    if (m0 >= cnt) return;
    const int n0 = blockIdx.x * 64;

    __shared__ u16 Bs[2][64 * 32];

    const int tid = threadIdx.x;
    const int lane = tid & 63, wid = tid >> 6;
    const int wm = wid * 16;
    const int lrow = lane & 15, lgrp = lane >> 4;
    const int soff = (lgrp ^ ((lrow >> 1) & 3)) * 8;

    const int gseg = ((tid & 3) ^ ((tid >> 3) & 3)) * 8;
    const u16* bpg = W2b + (size_t)e * HDIM * FDIM + (size_t)(n0 + (tid >> 2)) * FDIM + gseg;
    const u16* apg = G + ((size_t)e * NTOK + m0 + wm + lrow) * FDIM + lgrp * 8;

    fx4 acc[4];
    #pragma unroll
    for (int i = 0; i < 4; ++i) acc[i] = fx4{0.f, 0.f, 0.f, 0.f};

    gll16(bpg, &Bs[0][wid * 512]);
    bh8 a0 = *(const bh8*)(apg);
    bh8 a1;

    for (int k0 = 0; k0 < FDIM; k0 += 64) {
        __syncthreads();
        gll16(bpg + k0 + 32, &Bs[1][wid * 512]);
        a1 = *(const bh8*)(apg + k0 + 32);
        #pragma unroll
        for (int ni = 0; ni < 4; ++ni) {
            const bh8 bf = *(const bh8*)&Bs[0][(ni * 16 + lrow) * 32 + soff];
            acc[ni] = __builtin_amdgcn_mfma_f32_16x16x32_bf16(a0, bf, acc[ni], 0, 0, 0);
        }
        __syncthreads();
        if (k0 + 64 < FDIM) {
            gll16(bpg + k0 + 64, &Bs[0][wid * 512]);
            a0 = *(const bh8*)(apg + k0 + 64);
        }
        #pragma unroll
        for (int ni = 0; ni < 4; ++ni) {
            const bh8 bf = *(const bh8*)&Bs[1][(ni * 16 + lrow) * 32 + soff];
            acc[ni] = __builtin_amdgcn_mfma_f32_16x16x32_bf16(a1, bf, acc[ni], 0, 0, 0);
        }
    }

    #pragma unroll
    for (int j = 0; j < 4; ++j) {
        const int r = m0 + wm + lgrp * 4 + j;
        if (r < cnt) {
            const int ts = tokslot[e * NTOK + r];
            const float wgt = wtb[e * NTOK + r];
            const int tt = ts >> 1;
            const int sl = ts & 1;
            #pragma unroll
            for (int ni = 0; ni < 4; ++ni) {
                const int c = n0 + ni * 16 + lrow;
                MO[((size_t)sl * NTOK + tt) * HDIM + c] = acc[ni][j] * wgt;
            }
        }
    }
}

// ---------------------------------------------------------------- final add
__global__ __launch_bounds__(256)
void final_add_k(const float* __restrict__ A, const float* __restrict__ B0,
                 const float* __restrict__ B1, float* __restrict__ O) {
    const size_t i = ((size_t)blockIdx.x * 256 + threadIdx.x) * 4;
    const fx4 a = *(const fx4*)&A[i];
    const fx4 b = *(const fx4*)&B0[i];
    const fx4 c = *(const fx4*)&B1[i];
    fx4 r;
    #pragma unroll
    for (int k = 0; k < 4; ++k) r[k] = a[k] + b[k] + c[k];
    *(fx4*)&O[i] = r;
}

// ---------------------------------------------------------------- launcher
extern "C" void kernel_launch(void* const* d_in, const int* in_sizes, int n_in,
                              void* d_out, int out_size, void* d_ws, size_t ws_size,
                              hipStream_t stream) {
    const float* x   = (const float*)d_in[0];
    const float* ln1 = (const float*)d_in[2];
    const float* ln2 = (const float*)d_in[3];
    const float* wq  = (const float*)d_in[4];
    const float* wk  = (const float*)d_in[5];
    const float* wv  = (const float*)d_in[6];
    const float* wo  = (const float*)d_in[7];
    const float* gw  = (const float*)d_in[8];
    const float* w1  = (const float*)d_in[9];
    const float* w2  = (const float*)d_in[10];
    const float* w3  = (const float*)d_in[11];

    float* out_h = (float*)d_out;
    float* out_logits = out_h + (size_t)NTOK * HDIM;

    uint8_t* wsb = (uint8_t*)d_ws;
    size_t off = 0;
    auto alloc = [&](size_t bytes) -> void* {
        void* ptr = wsb + off;
        off = (off + bytes + 255) & ~(size_t)255;
        return ptr;
    };
    u16*   xn1    = (u16*)alloc((size_t)NTOK * HDIM * 2);
    u16*   qb     = (u16*)alloc((size_t)NTOK * 1024 * 2);
    u16*   kb     = (u16*)alloc((size_t)NTOK * 256 * 2);
    u16*   vb     = (u16*)alloc((size_t)NTOK * 256 * 2);
    u16*   ctxb   = (u16*)alloc((size_t)NTOK * 1024 * 2);
    float* hattn  = (float*)alloc((size_t)NTOK * HDIM * 4);
    u16*   xn2    = (u16*)alloc((size_t)NTOK * HDIM * 2);
    float* cosT   = (float*)alloc((size_t)NTOK * 32 * 4);
    float* sinT   = (float*)alloc((size_t)NTOK * 32 * 4);
    int*   counts = (int*)alloc(NE * 4);
    int*   tokslot= (int*)alloc((size_t)NE * NTOK * 4);
    float* wtb    = (float*)alloc((size_t)NE * NTOK * 4);
    u16*   gbuf   = (u16*)alloc((size_t)NE * NTOK * FDIM * 2);
    float* moeb   = (float*)alloc((size_t)2 * NTOK * HDIM * 4);
    u16*   wqb    = (u16*)alloc((size_t)1024 * HDIM * 2);
    u16*   wkb    = (u16*)alloc((size_t)256 * HDIM * 2);
    u16*   wvb    = (u16*)alloc((size_t)256 * HDIM * 2);
    u16*   wob    = (u16*)alloc((size_t)HDIM * 1024 * 2);
    u16*   w1b    = (u16*)alloc((size_t)NE * FDIM * HDIM * 2);
    u16*   w2b    = (u16*)alloc((size_t)NE * HDIM * FDIM * 2);
    u16*   w3b    = (u16*)alloc((size_t)NE * FDIM * HDIM * 2);

    hipMemsetAsync(counts, 0, NE * 4, stream);

    convert_k<<<512, 256, 0, stream>>>(wq, wqb, 1024 * HDIM / 8);
    convert_k<<<128, 256, 0, stream>>>(wk, wkb, 256 * HDIM / 8);
    convert_k<<<128, 256, 0, stream>>>(wv, wvb, 256 * HDIM / 8);
    convert_k<<<512, 256, 0, stream>>>(wo, wob, HDIM * 1024 / 8);
    convert_k<<<2048, 256, 0, stream>>>(w1, w1b, NE * FDIM * HDIM / 8);
    convert_k<<<2048, 256, 0, stream>>>(w2, w2b, NE * HDIM * FDIM / 8);
    convert_k<<<2048, 256, 0, stream>>>(w3, w3b, NE * FDIM * HDIM / 8);

    rope_table_k<<<256, 256, 0, stream>>>(cosT, sinT);
    rmsnorm_k<<<NTOK, 256, 0, stream>>>(x, ln1, xn1);
    gemm_bt<3><<<dim3(16, 32), 256, 0, stream>>>(xn1, wqb, qb, nullptr, 1024, HDIM, cosT, sinT);
    gemm_bt<3><<<dim3(4, 32), 256, 0, stream>>>(xn1, wkb, kb, nullptr, 256, HDIM, cosT, sinT);
    gemm_bt<2><<<dim3(4, 32), 256, 0, stream>>>(xn1, wvb, vb, nullptr, 256, HDIM, nullptr, nullptr);
    attn_kernel<<<dim3(16, 16), 256, 0, stream>>>(qb, kb, vb, ctxb);
    gemm_bt<1><<<dim3(16, 32), 256, 0, stream>>>(ctxb, wob, nullptr, hattn, 1024, 1024, x, nullptr);
    rmsnorm2_router_k<<<NTOK, 256, 0, stream>>>(hattn, ln2, gw, xn2, out_logits);
    router_topk_k<<<8, 256, 0, stream>>>(out_logits, counts, tokslot, wtb);
    moe_up_k<<<dim3(16, 32, NE), 256, 0, stream>>>(xn2, w1b, w3b, counts, tokslot, gbuf);
    moe_down_k<<<dim3(16, 32, NE), 256, 0, stream>>>(gbuf, w2b, counts, tokslot, wtb, moeb);
    final_add_k<<<NTOK, 256, 0, stream>>>(hattn, moeb, moeb + (size_t)NTOK * HDIM, out_h);
}

// Round 7
// 406.003 us; speedup vs baseline: 1.0806x; 1.0806x over previous
//
#include <hip/hip_runtime.h>
#include <hip/hip_bf16.h>
#include <cstdint>

typedef unsigned short u16;
typedef __attribute__((ext_vector_type(8))) short bh8;   // 8 bf16 (4 VGPR)
typedef __attribute__((ext_vector_type(4))) short sh4;   // 4 bf16
typedef __attribute__((ext_vector_type(4))) float fx4;

#define NTOK 2048
#define HDIM 1024
#define NE 8
#define FDIM 2048

#define VMCNT(n) asm volatile("s_waitcnt vmcnt(" #n ")" ::: "memory")
#define LGKM0()  asm volatile("s_waitcnt lgkmcnt(0)" ::: "memory")
#define SBAR()   __builtin_amdgcn_s_barrier()
#define SCB()    __builtin_amdgcn_sched_barrier(0)

__device__ __forceinline__ u16 f2bf(float f) {
    __hip_bfloat16 h = __float2bfloat16(f);
    return __builtin_bit_cast(u16, h);
}

// async global->LDS, 16B per lane. LDS dest is wave-uniform base (+lane*16 implicit).
__device__ __forceinline__ void gll16(const void* g, void* l) {
    __builtin_amdgcn_global_load_lds(
        (const __attribute__((address_space(1))) void*)g,
        (__attribute__((address_space(3))) void*)l, 16, 0, 0);
}

// ---------------------------------------------------------- f32 -> bf16 convert
__global__ __launch_bounds__(256)
void convert_k(const float* __restrict__ S, u16* __restrict__ D, int n8) {
    int i = blockIdx.x * 256 + threadIdx.x;
    const int stride = gridDim.x * 256;
    for (; i < n8; i += stride) {
        const fx4 a = *(const fx4*)&S[(size_t)i * 8];
        const fx4 b = *(const fx4*)&S[(size_t)i * 8 + 4];
        bh8 o;
        #pragma unroll
        for (int j = 0; j < 4; ++j) {
            o[j]     = (short)f2bf(a[j]);
            o[j + 4] = (short)f2bf(b[j]);
        }
        *(bh8*)&D[(size_t)i * 8] = o;
    }
}

// ---------------------------------------------------------------- rope table
__global__ __launch_bounds__(256)
void rope_table_k(float* __restrict__ cosT, float* __restrict__ sinT) {
    int idx = blockIdx.x * 256 + threadIdx.x;      // 2048*32
    int t = idx >> 5, i = idx & 31;
    float freq = powf(10000.0f, -(float)i * (1.0f / 32.0f));
    float ang = (float)t * freq;
    float s, c;
    sincosf(ang, &s, &c);
    cosT[idx] = c;
    sinT[idx] = s;
}

// ---------------------------------------------------------------- rmsnorm 1
__global__ __launch_bounds__(256)
void rmsnorm_k(const float* __restrict__ X, const float* __restrict__ W, u16* __restrict__ O) {
    const int t = blockIdx.x;
    const int tid = threadIdx.x;
    const fx4 v = *(const fx4*)&X[(size_t)t * HDIM + tid * 4];
    float ss = v[0]*v[0] + v[1]*v[1] + v[2]*v[2] + v[3]*v[3];
    #pragma unroll
    for (int o = 1; o < 64; o <<= 1) ss += __shfl_xor(ss, o);
    __shared__ float red[4];
    if ((tid & 63) == 0) red[tid >> 6] = ss;
    __syncthreads();
    const float inv = rsqrtf((red[0] + red[1] + red[2] + red[3]) * (1.0f / HDIM) + 1e-5f);
    const fx4 w = *(const fx4*)&W[tid * 4];
    sh4 o4;
    #pragma unroll
    for (int i = 0; i < 4; ++i) o4[i] = (short)f2bf(v[i] * inv * w[i]);
    *(sh4*)&O[(size_t)t * HDIM + tid * 4] = o4;
}

// -------------------------------------------- rmsnorm 2 + router logits (f32)
__global__ __launch_bounds__(256)
void rmsnorm2_router_k(const float* __restrict__ X, const float* __restrict__ W,
                       const float* __restrict__ GW, u16* __restrict__ O,
                       float* __restrict__ LOGI) {
    const int t = blockIdx.x;
    const int tid = threadIdx.x;
    const fx4 v = *(const fx4*)&X[(size_t)t * HDIM + tid * 4];
    float ss = v[0]*v[0] + v[1]*v[1] + v[2]*v[2] + v[3]*v[3];
    #pragma unroll
    for (int o = 1; o < 64; o <<= 1) ss += __shfl_xor(ss, o);
    __shared__ float red[4];
    if ((tid & 63) == 0) red[tid >> 6] = ss;
    __syncthreads();
    const float inv = rsqrtf((red[0] + red[1] + red[2] + red[3]) * (1.0f / HDIM) + 1e-5f);
    const fx4 w = *(const fx4*)&W[tid * 4];
    fx4 xn;
    #pragma unroll
    for (int i = 0; i < 4; ++i) xn[i] = v[i] * inv * w[i];
    sh4 o4;
    #pragma unroll
    for (int i = 0; i < 4; ++i) o4[i] = (short)f2bf(xn[i]);
    *(sh4*)&O[(size_t)t * HDIM + tid * 4] = o4;

    float part[NE];
    #pragma unroll
    for (int e = 0; e < NE; ++e) {
        const fx4 g = *(const fx4*)&GW[(size_t)e * HDIM + tid * 4];
        part[e] = g[0]*xn[0] + g[1]*xn[1] + g[2]*xn[2] + g[3]*xn[3];
    }
    #pragma unroll
    for (int e = 0; e < NE; ++e)
        #pragma unroll
        for (int o = 1; o < 64; o <<= 1) part[e] += __shfl_xor(part[e], o);
    __shared__ float red8[4][NE];
    if ((tid & 63) == 0) {
        #pragma unroll
        for (int e = 0; e < NE; ++e) red8[tid >> 6][e] = part[e];
    }
    __syncthreads();
    if (tid < NE)
        LOGI[(size_t)t * NE + tid] = red8[0][tid] + red8[1][tid] + red8[2][tid] + red8[3][tid];
}

// ---------------------------------------------------------------- router top2
__global__ __launch_bounds__(256)
void router_topk_k(const float* __restrict__ LOGI, int* __restrict__ counts,
                   int* __restrict__ tokslot, float* __restrict__ wtb) {
    const int t = blockIdx.x * 256 + threadIdx.x;
    float l[NE];
    #pragma unroll
    for (int e = 0; e < NE; ++e) l[e] = LOGI[(size_t)t * NE + e];
    int i0 = 0;
    #pragma unroll
    for (int e = 1; e < NE; ++e) if (l[e] > l[i0]) i0 = e;
    int i1 = (i0 == 0) ? 1 : 0;
    #pragma unroll
    for (int e = 0; e < NE; ++e) if (e != i0 && l[e] > l[i1]) i1 = e;
    float e1 = __expf(l[i1] - l[i0]);
    float w0 = 1.0f / (1.0f + e1);
    float w1 = 1.0f - w0;
    int p0 = atomicAdd(&counts[i0], 1);
    tokslot[i0 * NTOK + p0] = t * 2;
    wtb[i0 * NTOK + p0] = w0;
    int p1 = atomicAdd(&counts[i1], 1);
    tokslot[i1 * NTOK + p1] = t * 2 + 1;
    wtb[i1 * NTOK + p1] = w1;
}

// ------------------------------------------------------------- generic GEMM
// C[M,N] = A_bf16[M,K] @ B_bf16[N,K]^T ; 64x64 tile, 4 waves (wave = 16 rows).
// Counted-vmcnt dbuf gll pipeline (2 loads/phase, vmcnt(2)); XOR-swizzled LDS.
// K must be a multiple of 64.
// EPI: 1 = f32 + residual ; 2 = bf16 ; 3 = bf16 + RoPE
template<int EPI>
__global__ __launch_bounds__(256)
void gemm_bt(const u16* __restrict__ A, const u16* __restrict__ B,
             u16* __restrict__ Cb, float* __restrict__ Cf,
             const int N, const int K,
             const float* __restrict__ aux0, const float* __restrict__ aux1) {
    __shared__ u16 As[2][64 * 32];
    __shared__ u16 Bs[2][64 * 32];

    const int tid = threadIdx.x;
    const int lane = tid & 63;
    const int wid = tid >> 6;
    const int lrow = lane & 15, lgrp = lane >> 4;
    const int wm = wid * 16;
    const int soff = (lgrp ^ ((lrow >> 1) & 3)) * 8;

    const int m0 = blockIdx.y * 64;
    const int n0 = blockIdx.x * 64;

    const int gseg = ((tid & 3) ^ ((tid >> 3) & 3)) * 8;
    const u16* apg = A + (size_t)(m0 + (tid >> 2)) * K + gseg;
    const u16* bpg = B + (size_t)(n0 + (tid >> 2)) * K + gseg;

    fx4 acc[4];
    #pragma unroll
    for (int i = 0; i < 4; ++i) acc[i] = fx4{0.f, 0.f, 0.f, 0.f};

    gll16(apg, &As[0][wid * 512]);
    gll16(bpg, &Bs[0][wid * 512]);

    for (int k0 = 0; k0 < K; k0 += 64) {
        // phase 0: stage k0+32 -> buf1 ; compute buf0
        gll16(apg + k0 + 32, &As[1][wid * 512]);
        gll16(bpg + k0 + 32, &Bs[1][wid * 512]);
        VMCNT(2); SBAR(); SCB();
        {
            const bh8 af = *(const bh8*)&As[0][(wm + lrow) * 32 + soff];
            #pragma unroll
            for (int ni = 0; ni < 4; ++ni) {
                const bh8 bf = *(const bh8*)&Bs[0][(ni * 16 + lrow) * 32 + soff];
                acc[ni] = __builtin_amdgcn_mfma_f32_16x16x32_bf16(af, bf, acc[ni], 0, 0, 0);
            }
        }
        LGKM0(); SBAR();
        // phase 1: stage k0+64 -> buf0 (clamped dummy on last) ; compute buf1
        {
            const int kn = (k0 + 64 < K) ? k0 + 64 : k0;
            gll16(apg + kn, &As[0][wid * 512]);
            gll16(bpg + kn, &Bs[0][wid * 512]);
        }
        VMCNT(2); SBAR(); SCB();
        {
            const bh8 af = *(const bh8*)&As[1][(wm + lrow) * 32 + soff];
            #pragma unroll
            for (int ni = 0; ni < 4; ++ni) {
                const bh8 bf = *(const bh8*)&Bs[1][(ni * 16 + lrow) * 32 + soff];
                acc[ni] = __builtin_amdgcn_mfma_f32_16x16x32_bf16(af, bf, acc[ni], 0, 0, 0);
            }
        }
        LGKM0(); SBAR();
    }
    VMCNT(0);

    #pragma unroll
    for (int j = 0; j < 4; ++j) {
        const int r = m0 + wm + lgrp * 4 + j;
        if (EPI == 3) {
            #pragma unroll
            for (int ni = 0; ni < 2; ++ni) {
                const int d = ni * 16 + lrow;            // d < 32
                const float cv = aux0[r * 32 + d];
                const float sv = aux1[r * 32 + d];
                const float v0 = acc[ni][j];
                const float v1 = acc[ni + 2][j];
                Cb[(size_t)r * N + n0 + d]      = f2bf(v0 * cv - v1 * sv);
                Cb[(size_t)r * N + n0 + d + 32] = f2bf(v1 * cv + v0 * sv);
            }
        } else {
            #pragma unroll
            for (int ni = 0; ni < 4; ++ni) {
                const int c = n0 + ni * 16 + lrow;
                const float v = acc[ni][j];
                if (EPI == 1) Cf[(size_t)r * N + c] = v + aux0[(size_t)r * N + c];
                if (EPI == 2) Cb[(size_t)r * N + c] = f2bf(v);
            }
        }
    }
}

// --------------------------------------------------------- flash attention
__global__ __launch_bounds__(256)
void attn_kernel(const u16* __restrict__ Q, const u16* __restrict__ Kg,
                 const u16* __restrict__ Vg, u16* __restrict__ O) {
    const int qt = blockIdx.x;
    const int h = blockIdx.y;
    const int kvh = h >> 2;

    const int tid = threadIdx.x;
    const int lane = tid & 63;
    const int wid = tid >> 6;
    const int lrow = lane & 15, lgrp = lane >> 4;

    __shared__ u16 Ks[64 * 72];
    __shared__ u16 Vs[64 * 72];
    __shared__ u16 Ps[4][32 * 72];

    const int qbase = qt * 128 + wid * 32;

    bh8 qf[2][2];
    #pragma unroll
    for (int mi = 0; mi < 2; ++mi)
        #pragma unroll
        for (int kf = 0; kf < 2; ++kf)
            qf[mi][kf] = *(const bh8*)&Q[(size_t)(qbase + mi * 16 + lrow) * 1024 + h * 64 + kf * 32 + lgrp * 8];

    fx4 acc[2][4];
    #pragma unroll
    for (int mi = 0; mi < 2; ++mi)
        #pragma unroll
        for (int ni = 0; ni < 4; ++ni) acc[mi][ni] = fx4{0.f, 0.f, 0.f, 0.f};
    float mrun[2][4], lrun[2][4];
    #pragma unroll
    for (int mi = 0; mi < 2; ++mi)
        #pragma unroll
        for (int j = 0; j < 4; ++j) { mrun[mi][j] = -1e30f; lrun[mi][j] = 0.f; }

    const int srow = tid >> 2;
    const int sseg = (tid & 3) * 16;

    const int ntiles = qt * 2 + 2;

    size_t goff = (size_t)(srow) * 256 + kvh * 64 + sseg;
    bh8 kva = *(const bh8*)&Kg[goff];
    bh8 kvb = *(const bh8*)&Kg[goff + 8];
    bh8 vva = *(const bh8*)&Vg[goff];
    bh8 vvb = *(const bh8*)&Vg[goff + 8];

    for (int it = 0; it < ntiles; ++it) {
        const int kv0 = it * 64;
        __syncthreads();
        *(bh8*)&Ks[srow * 72 + sseg] = kva;
        *(bh8*)&Ks[srow * 72 + sseg + 8] = kvb;
        #pragma unroll
        for (int jj = 0; jj < 8; ++jj) {
            Vs[(sseg + jj) * 72 + srow]     = (u16)vva[jj];
            Vs[(sseg + 8 + jj) * 72 + srow] = (u16)vvb[jj];
        }
        __syncthreads();

        const int itn = (it + 1 < ntiles) ? it + 1 : it;
        const size_t goff2 = (size_t)(itn * 64 + srow) * 256 + kvh * 64 + sseg;
        kva = *(const bh8*)&Kg[goff2];
        kvb = *(const bh8*)&Kg[goff2 + 8];
        vva = *(const bh8*)&Vg[goff2];
        vvb = *(const bh8*)&Vg[goff2 + 8];

        fx4 s[2][4];
        #pragma unroll
        for (int mi = 0; mi < 2; ++mi)
            #pragma unroll
            for (int nf = 0; nf < 4; ++nf) s[mi][nf] = fx4{0.f, 0.f, 0.f, 0.f};
        #pragma unroll
        for (int kf = 0; kf < 2; ++kf) {
            bh8 kfr[4];
            #pragma unroll
            for (int nf = 0; nf < 4; ++nf)
                kfr[nf] = *(const bh8*)&Ks[(nf * 16 + lrow) * 72 + kf * 32 + lgrp * 8];
            #pragma unroll
            for (int mi = 0; mi < 2; ++mi)
                #pragma unroll
                for (int nf = 0; nf < 4; ++nf)
                    s[mi][nf] = __builtin_amdgcn_mfma_f32_16x16x32_bf16(qf[mi][kf], kfr[nf], s[mi][nf], 0, 0, 0);
        }

        #pragma unroll
        for (int mi = 0; mi < 2; ++mi)
            #pragma unroll
            for (int nf = 0; nf < 4; ++nf)
                #pragma unroll
                for (int j = 0; j < 4; ++j) {
                    const int qr = qbase + mi * 16 + lgrp * 4 + j;
                    const int kp = kv0 + nf * 16 + lrow;
                    const float v = s[mi][nf][j] * 0.125f;
                    s[mi][nf][j] = (kp > qr) ? -1e30f : v;
                }

        #pragma unroll
        for (int mi = 0; mi < 2; ++mi)
            #pragma unroll
            for (int j = 0; j < 4; ++j) {
                float mx = fmaxf(fmaxf(s[mi][0][j], s[mi][1][j]), fmaxf(s[mi][2][j], s[mi][3][j]));
                #pragma unroll
                for (int o = 1; o < 16; o <<= 1) mx = fmaxf(mx, __shfl_xor(mx, o));
                const float mnew = fmaxf(mrun[mi][j], mx);
                const float alpha = __expf(mrun[mi][j] - mnew);
                mrun[mi][j] = mnew;
                float rsum = 0.f;
                #pragma unroll
                for (int nf = 0; nf < 4; ++nf) {
                    const float p = __expf(s[mi][nf][j] - mnew);
                    s[mi][nf][j] = p;
                    rsum += p;
                }
                #pragma unroll
                for (int o = 1; o < 16; o <<= 1) rsum += __shfl_xor(rsum, o);
                lrun[mi][j] = lrun[mi][j] * alpha + rsum;
                #pragma unroll
                for (int ni = 0; ni < 4; ++ni) acc[mi][ni][j] *= alpha;
            }

        u16* pw = Ps[wid];
        #pragma unroll
        for (int mi = 0; mi < 2; ++mi)
            #pragma unroll
            for (int nf = 0; nf < 4; ++nf)
                #pragma unroll
                for (int j = 0; j < 4; ++j)
                    pw[(mi * 16 + lgrp * 4 + j) * 72 + nf * 16 + lrow] = f2bf(s[mi][nf][j]);

        #pragma unroll
        for (int kf = 0; kf < 2; ++kf) {
            bh8 pa[2];
            #pragma unroll
            for (int mi = 0; mi < 2; ++mi)
                pa[mi] = *(const bh8*)&pw[(mi * 16 + lrow) * 72 + kf * 32 + lgrp * 8];
            #pragma unroll
            for (int ni = 0; ni < 4; ++ni) {
                bh8 vb = *(const bh8*)&Vs[(ni * 16 + lrow) * 72 + kf * 32 + lgrp * 8];
                #pragma unroll
                for (int mi = 0; mi < 2; ++mi)
                    acc[mi][ni] = __builtin_amdgcn_mfma_f32_16x16x32_bf16(pa[mi], vb, acc[mi][ni], 0, 0, 0);
            }
        }
    }

    #pragma unroll
    for (int mi = 0; mi < 2; ++mi)
        #pragma unroll
        for (int j = 0; j < 4; ++j) {
            const float inv = 1.0f / lrun[mi][j];
            const int r = qbase + mi * 16 + lgrp * 4 + j;
            #pragma unroll
            for (int ni = 0; ni < 4; ++ni)
                O[(size_t)r * 1024 + h * 64 + ni * 16 + lrow] = f2bf(acc[mi][ni][j] * inv);
        }
}

// ------------------------------------------------- MoE up (w1,w3 + SiLU*mul)
// 64x128 tile, 4 waves (2x2; wave = 32m x 64n). A,B1,B3 via swizzled gll,
// counted-vmcnt dbuf (5 loads/phase, vmcnt(5)), 40KB LDS.
__global__ __launch_bounds__(256)
void moe_up_k(const u16* __restrict__ X, const u16* __restrict__ W1b,
              const u16* __restrict__ W3b, const int* __restrict__ counts,
              const int* __restrict__ tokslot, u16* __restrict__ G) {
    const int e = blockIdx.z;
    const int cnt = counts[e];
    const int m0 = blockIdx.y * 64;
    if (m0 >= cnt) return;
    const int n0 = blockIdx.x * 128;

    __shared__ u16 As[2][64 * 32];
    __shared__ u16 B1s[2][128 * 32];
    __shared__ u16 B3s[2][128 * 32];

    const int tid = threadIdx.x;
    const int lane = tid & 63, wid = tid >> 6;
    const int wm = (wid >> 1) * 32, wn = (wid & 1) * 64;
    const int lrow = lane & 15, lgrp = lane >> 4;
    const int soff = (lgrp ^ ((lrow >> 1) & 3)) * 8;

    const int gseg = ((tid & 3) ^ ((tid >> 3) & 3)) * 8;
    const int arow = m0 + (tid >> 2);
    const int tok = (arow < cnt) ? (tokslot[e * NTOK + arow] >> 1) : 0;
    const u16* apg = X + (size_t)tok * HDIM + gseg;
    const size_t eoff = (size_t)e * FDIM * HDIM;
    const u16* b1pg = W1b + eoff + (size_t)(n0 + (tid >> 2)) * HDIM + gseg;
    const u16* b3pg = W3b + eoff + (size_t)(n0 + (tid >> 2)) * HDIM + gseg;
    const size_t rr = (size_t)64 * HDIM;

    fx4 acc1[2][4], acc3[2][4];
    #pragma unroll
    for (int i = 0; i < 2; ++i)
        #pragma unroll
        for (int j = 0; j < 4; ++j) {
            acc1[i][j] = fx4{0.f, 0.f, 0.f, 0.f};
            acc3[i][j] = fx4{0.f, 0.f, 0.f, 0.f};
        }

    gll16(apg, &As[0][wid * 512]);
    gll16(b1pg, &B1s[0][wid * 512]);
    gll16(b1pg + rr, &B1s[0][2048 + wid * 512]);
    gll16(b3pg, &B3s[0][wid * 512]);
    gll16(b3pg + rr, &B3s[0][2048 + wid * 512]);

#define MOE_UP_COMPUTE(BUF)                                                          \
    {                                                                                \
        bh8 af[2], b1f[4], b3f[4];                                                   \
        _Pragma("unroll")                                                            \
        for (int mi = 0; mi < 2; ++mi)                                               \
            af[mi] = *(const bh8*)&As[BUF][(wm + mi * 16 + lrow) * 32 + soff];       \
        _Pragma("unroll")                                                            \
        for (int ni = 0; ni < 4; ++ni) {                                             \
            b1f[ni] = *(const bh8*)&B1s[BUF][(wn + ni * 16 + lrow) * 32 + soff];     \
            b3f[ni] = *(const bh8*)&B3s[BUF][(wn + ni * 16 + lrow) * 32 + soff];     \
        }                                                                            \
        _Pragma("unroll")                                                            \
        for (int mi = 0; mi < 2; ++mi)                                               \
            _Pragma("unroll")                                                        \
            for (int ni = 0; ni < 4; ++ni) {                                         \
                acc1[mi][ni] = __builtin_amdgcn_mfma_f32_16x16x32_bf16(af[mi], b1f[ni], acc1[mi][ni], 0, 0, 0); \
                acc3[mi][ni] = __builtin_amdgcn_mfma_f32_16x16x32_bf16(af[mi], b3f[ni], acc3[mi][ni], 0, 0, 0); \
            }                                                                        \
    }

    for (int k0 = 0; k0 < HDIM; k0 += 64) {
        // phase 0: stage k0+32 -> buf1 ; compute buf0
        {
            const int kn = k0 + 32;
            gll16(apg + kn, &As[1][wid * 512]);
            gll16(b1pg + kn, &B1s[1][wid * 512]);
            gll16(b1pg + rr + kn, &B1s[1][2048 + wid * 512]);
            gll16(b3pg + kn, &B3s[1][wid * 512]);
            gll16(b3pg + rr + kn, &B3s[1][2048 + wid * 512]);
        }
        VMCNT(5); SBAR(); SCB();
        MOE_UP_COMPUTE(0)
        LGKM0(); SBAR();
        // phase 1: stage k0+64 -> buf0 (dummy on last) ; compute buf1
        {
            const int kn = (k0 + 64 < HDIM) ? k0 + 64 : k0;
            gll16(apg + kn, &As[0][wid * 512]);
            gll16(b1pg + kn, &B1s[0][wid * 512]);
            gll16(b1pg + rr + kn, &B1s[0][2048 + wid * 512]);
            gll16(b3pg + kn, &B3s[0][wid * 512]);
            gll16(b3pg + rr + kn, &B3s[0][2048 + wid * 512]);
        }
        VMCNT(5); SBAR(); SCB();
        MOE_UP_COMPUTE(1)
        LGKM0(); SBAR();
    }
    VMCNT(0);
#undef MOE_UP_COMPUTE

    #pragma unroll
    for (int mi = 0; mi < 2; ++mi)
        #pragma unroll
        for (int j = 0; j < 4; ++j) {
            const int r = m0 + wm + mi * 16 + lgrp * 4 + j;
            if (r < cnt) {
                #pragma unroll
                for (int ni = 0; ni < 4; ++ni) {
                    const int c = n0 + wn + ni * 16 + lrow;
                    const float h1 = acc1[mi][ni][j];
                    const float h3 = acc3[mi][ni][j];
                    const float gv = h1 / (1.0f + __expf(-h1)) * h3;
                    G[((size_t)e * NTOK + r) * FDIM + c] = f2bf(gv);
                }
            }
        }
}

// -------------------------------------------------- MoE down (scaled scatter)
// 64x64 tile, 4 waves (wave = 16 rows), K=2048. Counted-vmcnt dbuf gll, swizzled.
__global__ __launch_bounds__(256)
void moe_down_k(const u16* __restrict__ G, const u16* __restrict__ W2b,
                const int* __restrict__ counts, const int* __restrict__ tokslot,
                const float* __restrict__ wtb, float* __restrict__ MO) {
    const int e = blockIdx.z;
    const int cnt = counts[e];
    const int m0 = blockIdx.y * 64;
    if (m0 >= cnt) return;
    const int n0 = blockIdx.x * 64;

    __shared__ u16 As[2][64 * 32];
    __shared__ u16 Bs[2][64 * 32];

    const int tid = threadIdx.x;
    const int lane = tid & 63, wid = tid >> 6;
    const int wm = wid * 16;
    const int lrow = lane & 15, lgrp = lane >> 4;
    const int soff = (lgrp ^ ((lrow >> 1) & 3)) * 8;

    const int gseg = ((tid & 3) ^ ((tid >> 3) & 3)) * 8;
    const u16* apg = G + ((size_t)e * NTOK + m0 + (tid >> 2)) * FDIM + gseg;
    const u16* bpg = W2b + (size_t)e * HDIM * FDIM + (size_t)(n0 + (tid >> 2)) * FDIM + gseg;

    fx4 acc[4];
    #pragma unroll
    for (int i = 0; i < 4; ++i) acc[i] = fx4{0.f, 0.f, 0.f, 0.f};

    gll16(apg, &As[0][wid * 512]);
    gll16(bpg, &Bs[0][wid * 512]);

    for (int k0 = 0; k0 < FDIM; k0 += 64) {
        gll16(apg + k0 + 32, &As[1][wid * 512]);
        gll16(bpg + k0 + 32, &Bs[1][wid * 512]);
        VMCNT(2); SBAR(); SCB();
        {
            const bh8 af = *(const bh8*)&As[0][(wm + lrow) * 32 + soff];
            #pragma unroll
            for (int ni = 0; ni < 4; ++ni) {
                const bh8 bf = *(const bh8*)&Bs[0][(ni * 16 + lrow) * 32 + soff];
                acc[ni] = __builtin_amdgcn_mfma_f32_16x16x32_bf16(af, bf, acc[ni], 0, 0, 0);
            }
        }
        LGKM0(); SBAR();
        {
            const int kn = (k0 + 64 < FDIM) ? k0 + 64 : k0;
            gll16(apg + kn, &As[0][wid * 512]);
            gll16(bpg + kn, &Bs[0][wid * 512]);
        }
        VMCNT(2); SBAR(); SCB();
        {
            const bh8 af = *(const bh8*)&As[1][(wm + lrow) * 32 + soff];
            #pragma unroll
            for (int ni = 0; ni < 4; ++ni) {
                const bh8 bf = *(const bh8*)&Bs[1][(ni * 16 + lrow) * 32 + soff];
                acc[ni] = __builtin_amdgcn_mfma_f32_16x16x32_bf16(af, bf, acc[ni], 0, 0, 0);
            }
        }
        LGKM0(); SBAR();
    }
    VMCNT(0);

    #pragma unroll
    for (int j = 0; j < 4; ++j) {
        const int r = m0 + wm + lgrp * 4 + j;
        if (r < cnt) {
            const int ts = tokslot[e * NTOK + r];
            const float wgt = wtb[e * NTOK + r];
            const int tt = ts >> 1;
            const int sl = ts & 1;
            #pragma unroll
            for (int ni = 0; ni < 4; ++ni) {
                const int c = n0 + ni * 16 + lrow;
                MO[((size_t)sl * NTOK + tt) * HDIM + c] = acc[ni][j] * wgt;
            }
        }
    }
}

// ---------------------------------------------------------------- final add
__global__ __launch_bounds__(256)
void final_add_k(const float* __restrict__ A, const float* __restrict__ B0,
                 const float* __restrict__ B1, float* __restrict__ O) {
    const size_t i = ((size_t)blockIdx.x * 256 + threadIdx.x) * 4;
    const fx4 a = *(const fx4*)&A[i];
    const fx4 b = *(const fx4*)&B0[i];
    const fx4 c = *(const fx4*)&B1[i];
    fx4 r;
    #pragma unroll
    for (int k = 0; k < 4; ++k) r[k] = a[k] + b[k] + c[k];
    *(fx4*)&O[i] = r;
}

// ---------------------------------------------------------------- launcher
extern "C" void kernel_launch(void* const* d_in, const int* in_sizes, int n_in,
                              void* d_out, int out_size, void* d_ws, size_t ws_size,
                              hipStream_t stream) {
    const float* x   = (const float*)d_in[0];
    const float* ln1 = (const float*)d_in[2];
    const float* ln2 = (const float*)d_in[3];
    const float* wq  = (const float*)d_in[4];
    const float* wk  = (const float*)d_in[5];
    const float* wv  = (const float*)d_in[6];
    const float* wo  = (const float*)d_in[7];
    const float* gw  = (const float*)d_in[8];
    const float* w1  = (const float*)d_in[9];
    const float* w2  = (const float*)d_in[10];
    const float* w3  = (const float*)d_in[11];

    float* out_h = (float*)d_out;
    float* out_logits = out_h + (size_t)NTOK * HDIM;

    uint8_t* wsb = (uint8_t*)d_ws;
    size_t off = 0;
    auto alloc = [&](size_t bytes) -> void* {
        void* ptr = wsb + off;
        off = (off + bytes + 255) & ~(size_t)255;
        return ptr;
    };
    u16*   xn1    = (u16*)alloc((size_t)NTOK * HDIM * 2);
    u16*   qb     = (u16*)alloc((size_t)NTOK * 1024 * 2);
    u16*   kb     = (u16*)alloc((size_t)NTOK * 256 * 2);
    u16*   vb     = (u16*)alloc((size_t)NTOK * 256 * 2);
    u16*   ctxb   = (u16*)alloc((size_t)NTOK * 1024 * 2);
    float* hattn  = (float*)alloc((size_t)NTOK * HDIM * 4);
    u16*   xn2    = (u16*)alloc((size_t)NTOK * HDIM * 2);
    float* cosT   = (float*)alloc((size_t)NTOK * 32 * 4);
    float* sinT   = (float*)alloc((size_t)NTOK * 32 * 4);
    int*   counts = (int*)alloc(NE * 4);
    int*   tokslot= (int*)alloc((size_t)NE * NTOK * 4);
    float* wtb    = (float*)alloc((size_t)NE * NTOK * 4);
    u16*   gbuf   = (u16*)alloc((size_t)NE * NTOK * FDIM * 2);
    float* moeb   = (float*)alloc((size_t)2 * NTOK * HDIM * 4);
    u16*   wqb    = (u16*)alloc((size_t)1024 * HDIM * 2);
    u16*   wkb    = (u16*)alloc((size_t)256 * HDIM * 2);
    u16*   wvb    = (u16*)alloc((size_t)256 * HDIM * 2);
    u16*   wob    = (u16*)alloc((size_t)HDIM * 1024 * 2);
    u16*   w1b    = (u16*)alloc((size_t)NE * FDIM * HDIM * 2);
    u16*   w2b    = (u16*)alloc((size_t)NE * HDIM * FDIM * 2);
    u16*   w3b    = (u16*)alloc((size_t)NE * FDIM * HDIM * 2);

    hipMemsetAsync(counts, 0, NE * 4, stream);

    convert_k<<<512, 256, 0, stream>>>(wq, wqb, 1024 * HDIM / 8);
    convert_k<<<128, 256, 0, stream>>>(wk, wkb, 256 * HDIM / 8);
    convert_k<<<128, 256, 0, stream>>>(wv, wvb, 256 * HDIM / 8);
    convert_k<<<512, 256, 0, stream>>>(wo, wob, HDIM * 1024 / 8);
    convert_k<<<2048, 256, 0, stream>>>(w1, w1b, NE * FDIM * HDIM / 8);
    convert_k<<<2048, 256, 0, stream>>>(w2, w2b, NE * HDIM * FDIM / 8);
    convert_k<<<2048, 256, 0, stream>>>(w3, w3b, NE * FDIM * HDIM / 8);

    rope_table_k<<<256, 256, 0, stream>>>(cosT, sinT);
    rmsnorm_k<<<NTOK, 256, 0, stream>>>(x, ln1, xn1);
    gemm_bt<3><<<dim3(16, 32), 256, 0, stream>>>(xn1, wqb, qb, nullptr, 1024, HDIM, cosT, sinT);
    gemm_bt<3><<<dim3(4, 32), 256, 0, stream>>>(xn1, wkb, kb, nullptr, 256, HDIM, cosT, sinT);
    gemm_bt<2><<<dim3(4, 32), 256, 0, stream>>>(xn1, wvb, vb, nullptr, 256, HDIM, nullptr, nullptr);
    attn_kernel<<<dim3(16, 16), 256, 0, stream>>>(qb, kb, vb, ctxb);
    gemm_bt<1><<<dim3(16, 32), 256, 0, stream>>>(ctxb, wob, nullptr, hattn, 1024, 1024, x, nullptr);
    rmsnorm2_router_k<<<NTOK, 256, 0, stream>>>(hattn, ln2, gw, xn2, out_logits);
    router_topk_k<<<8, 256, 0, stream>>>(out_logits, counts, tokslot, wtb);
    moe_up_k<<<dim3(16, 32, NE), 256, 0, stream>>>(xn2, w1b, w3b, counts, tokslot, gbuf);
    moe_down_k<<<dim3(16, 32, NE), 256, 0, stream>>>(gbuf, w2b, counts, tokslot, wtb, moeb);
    final_add_k<<<NTOK, 256, 0, stream>>>(hattn, moeb, moeb + (size_t)NTOK * HDIM, out_h);
}